// Round 1
// 463.766 us; speedup vs baseline: 1.0138x; 1.0138x over previous
//
#include <hip/hip_runtime.h>

#define SEQ 1024
#define BN  512
#define NT  64

__global__ void zero_out_kernel(float* o) { o[0] = 0.0f; }

// lane-broadcast: v_readlane_b32 -> SGPR, feeds v_fmac_f32 (1 SGPR src is legal)
__device__ __forceinline__ float rlf(float v, int l) {
    return __int_as_float(__builtin_amdgcn_readlane(__float_as_int(v), l));
}

#define RPT64(M) \
  M(0) M(1) M(2) M(3) M(4) M(5) M(6) M(7) M(8) M(9) \
  M(10) M(11) M(12) M(13) M(14) M(15) M(16) M(17) M(18) M(19) \
  M(20) M(21) M(22) M(23) M(24) M(25) M(26) M(27) M(28) M(29) \
  M(30) M(31) M(32) M(33) M(34) M(35) M(36) M(37) M(38) M(39) \
  M(40) M(41) M(42) M(43) M(44) M(45) M(46) M(47) M(48) M(49) \
  M(50) M(51) M(52) M(53) M(54) M(55) M(56) M(57) M(58) M(59) \
  M(60) M(61) M(62) M(63)

// E[i][lane] = exp(T[i][lane]) as 64 NAMED scalars (static access -> VGPRs)
#define EDECL(i) const float E##i = __expf(trans[(i) * NT + lane]);

// 8 broadcasts + 8 FMAs into 8 independent chains (depth 8 across groups):
// readlane has no memory latency -> the recurrence never touches the DS pipe.
#define G8(i0,i1,i2,i3,i4,i5,i6,i7) {        \
    a0 = fmaf(rlf(u,i0), E##i0, a0);         \
    a1 = fmaf(rlf(u,i1), E##i1, a1);         \
    a2 = fmaf(rlf(u,i2), E##i2, a2);         \
    a3 = fmaf(rlf(u,i3), E##i3, a3);         \
    a4 = fmaf(rlf(u,i4), E##i4, a4);         \
    a5 = fmaf(rlf(u,i5), E##i5, a5);         \
    a6 = fmaf(rlf(u,i6), E##i6, a6);         \
    a7 = fmaf(rlf(u,i7), E##i7, a7);         \
  }

extern "C" __global__ __launch_bounds__(64, 1)
void crf_kernel(const float* __restrict__ emis,
                const int*   __restrict__ tags,
                const int*   __restrict__ mask,
                const float* __restrict__ startT,
                const float* __restrict__ endT,
                const float* __restrict__ trans,
                float* __restrict__ out)
{
    const int b    = blockIdx.x;
    const int lane = threadIdx.x;

    // LDS is now OFF the recurrence critical path: only the numerator
    // transition row (Trow) and packed tag|mask words live here, both
    // prefetched one full step (~300 cy) ahead of their use.
    __shared__ __align__(16) float strans[NT * NT];
    __shared__ int spk[SEQ];

    // ---- one-time staging (single wave, in-order DS, no barriers) ----
    {
        const float4* t4 = (const float4*)trans;
        float4* s4 = (float4*)strans;
        #pragma unroll
        for (int k = 0; k < 16; ++k)
            s4[k * NT + lane] = t4[k * NT + lane];
    }
    #pragma unroll
    for (int c = 0; c < SEQ / NT; ++c) {
        int t = c * NT + lane;
        spk[t] = (tags[t * BN + b] & 0xFFFF) | (mask[t * BN + b] << 16);
    }
    __threadfence_block();

    // ---- E in registers: 64 named floats (64 VGPRs) ----
    RPT64(EDECL)

    // ---- t = 0 init ----
    float em0    = emis[(0 * BN + b) * NT + lane];
    int   tg_p   = spk[0] & 0xFFFF;
    float alpha0 = startT[lane] + em0;
    float M = __int_as_float(__builtin_amdgcn_readfirstlane(__float_as_int(alpha0)));
    float u = __expf(alpha0 - M);            // u_0 at lane 0 == 1
    float score = (lane == tg_p) ? alpha0 : 0.0f;
    int   lt    = tg_p;
    int   esum  = 0;

    // next-step prefetches (land during the FMA phase of the prior step)
    int   pkC   = spk[1];
    float TrowC = strans[tg_p * NT + lane];

    // ---- depth-4 emissions prefetch (the ONLY vmem in the loop) ----
    float emA = emis[(1 * BN + b) * NT + lane];
    float emB = emis[(2 * BN + b) * NT + lane];
    float emC = emis[(3 * BN + b) * NT + lane];
    float emD = emis[(4 * BN + b) * NT + lane];

    #pragma unroll 4
    for (int t = 1; t < SEQ; ++t) {
        const float em_t = emA;
        emA = emB; emB = emC; emC = emD;
        int tn = t + 4; if (tn > SEQ - 1) tn = SEQ - 1;
        emD = emis[(tn * BN + b) * NT + lane];

        const int   pk   = pkC;                  // tag | mask<<16 (prefetched)
        const int   tg_t = pk & 0xFFFF;
        const int   mk_t = pk >> 16;
        const float Trow = TrowC;                // strans[tag_{t-1}][lane] (prefetched)

        // issue next step's DS reads now; consumed ~300 cy from here
        int tp = t + 1; if (tp > SEQ - 1) tp = SEQ - 1;
        pkC   = spk[tp];
        TrowC = strans[tg_t * NT + lane];        // conflict-free stride-1 b32

        const float w = __expf(em_t);            // off the u-chain

        // s_j = sum_i u_i * E[i][j]: 64 readlane broadcasts x 64 v_fmac_f32,
        // 8 independent chains, no LDS round trip on the recurrence
        float a0=0.f,a1=0.f,a2=0.f,a3=0.f,a4=0.f,a5=0.f,a6=0.f,a7=0.f;
        G8( 0, 1, 2, 3, 4, 5, 6, 7)
        G8( 8, 9,10,11,12,13,14,15)
        G8(16,17,18,19,20,21,22,23)
        G8(24,25,26,27,28,29,30,31)
        G8(32,33,34,35,36,37,38,39)
        G8(40,41,42,43,44,45,46,47)
        G8(48,49,50,51,52,53,54,55)
        G8(56,57,58,59,60,61,62,63)
        float s  = ((a0 + a1) + (a2 + a3)) + ((a4 + a5) + (a6 + a7));
        float sw = s * w;

        if (mk_t) {                               // wave-uniform
            u = sw;
            if (lane == tg_t) score += em_t + Trow;
            lt = tg_t;
        }

        // deferred exponent renorm: every 4th step only (power-of-2 scaling is
        // exact; s is a sum of positives so cross-lane spread of u stays ~22
        // bits -> no overflow/underflow risk across 4 unrenormed steps)
        if ((t & 3) == 0) {
            int e = (__builtin_amdgcn_readfirstlane(__float_as_int(u)) >> 23) & 255;
            u = ldexpf(u, 127 - e);
            esum += e - 127;
        }
        tg_p = tg_t; (void)tg_p;
    }

    // ---- epilogue ----
    if (lane == lt) score += endT[lane];
    float v  = u * __expf(endT[lane]);
    float sp = score;
    #pragma unroll
    for (int off = 32; off > 0; off >>= 1) {
        v  += __shfl_xor(v,  off, 64);
        sp += __shfl_xor(sp, off, 64);
    }
    if (lane == 0) {
        float denom = M + (float)esum * 0.69314718055994531f + __logf(v);
        atomicAdd(out, sp - denom);
    }
}

extern "C" void kernel_launch(void* const* d_in, const int* in_sizes, int n_in,
                              void* d_out, int out_size, void* d_ws, size_t ws_size,
                              hipStream_t stream)
{
    const float* emis   = (const float*)d_in[0];
    const int*   tags   = (const int*)  d_in[1];
    const int*   mask   = (const int*)  d_in[2];
    const float* startT = (const float*)d_in[3];
    const float* endT   = (const float*)d_in[4];
    const float* trans  = (const float*)d_in[5];
    float* out = (float*)d_out;

    zero_out_kernel<<<1, 1, 0, stream>>>(out);
    crf_kernel<<<dim3(BN), dim3(NT), 0, stream>>>(emis, tags, mask,
                                                  startT, endT, trans, out);
}